// Round 7
// baseline (234.974 us; speedup 1.0000x reference)
//
#include <hip/hip_runtime.h>
#include <hip/hip_bf16.h>

#define EPS 1e-5f

typedef __bf16 bf16x8 __attribute__((ext_vector_type(8)));
typedef float f32x4 __attribute__((ext_vector_type(4)));

__device__ __forceinline__ float hsw(float x){
    float t = fminf(fmaxf(x + 3.f, 0.f), 6.f);
    return x * t * (1.f/6.f);
}
__device__ __forceinline__ float sigm(float x){ return 1.f/(1.f + expf(-x)); }

// shift_in is analytically s = 64*((v+c)%25) + c  -> x[n,c,t,v] = x0[n,c,t,(v+c)%25].
// K1': pure reduce. Stage x0 tile in LDS; compute T0 partials (u-space, no gather)
// and view_pre via rotated weights Wv[(u-c)%25]. No x_perm materialization.
__global__ __launch_bounds__(256) void k1_viewtime(
    const float* __restrict__ x0, const float* __restrict__ Wv,
    const float* __restrict__ Wt, float* __restrict__ view_pre,
    float* __restrict__ t0_part, float* __restrict__ view_part)
{
    const int tc = blockIdx.x, n = blockIdx.y, t0 = tc*12;
    const int tid = threadIdx.x;
    __shared__ alignas(16) unsigned char smem[64*302*2];   // 38656 B
    __shared__ float rs[8];
    __shared__ float WvL[32];
    __hip_bfloat16* lx = (__hip_bfloat16*)smem;             // [c][tt*25+u], stride 302
    float* red = (float*)smem;                              // [w*64+c][13] after lx dead
    if (tid < 25) WvL[tid] = Wv[tid];
    const float* xb = x0 + n*480000 + t0*25;
    for (int i = tid; i < 4800; i += 256){
        int row = i/75, c4 = i - row*75;
        float4 f = *reinterpret_cast<const float4*>(xb + row*7500 + c4*4);
        union { uint2 u; __hip_bfloat16 h[4]; } pk;
        pk.h[0]=__float2bfloat16(f.x); pk.h[1]=__float2bfloat16(f.y);
        pk.h[2]=__float2bfloat16(f.z); pk.h[3]=__float2bfloat16(f.w);
        int base = row*302 + c4*4;
        *reinterpret_cast<unsigned*>(&lx[base])   = pk.u.x;
        *reinterpret_cast<unsigned*>(&lx[base+2]) = pk.u.y;
    }
    float wt[12];
    #pragma unroll
    for (int tt=0;tt<12;tt++) wt[tt] = Wt[t0+tt];
    __syncthreads();
    const int c = tid & 63, ug = tid >> 6;
    const int cm = c - ((c>=50)?50:((c>=25)?25:0));
    float vacc[12];
    #pragma unroll
    for (int tt=0;tt<12;tt++) vacc[tt]=0.f;
    for (int k=0;k<7;k++){
        int u = ug + 4*k;
        if (u < 25){
            int mm = u - cm; if (mm < 0) mm += 25;
            float wv = WvL[mm];
            int base = c*302 + u;
            float tacc = 0.f;
            #pragma unroll
            for (int tt=0;tt<12;tt++){
                float val = __bfloat162float(lx[base + tt*25]);
                tacc += wt[tt]*val;
                vacc[tt] += wv*val;
            }
            t0_part[(n*25+tc)*1600 + c*25 + u] = tacc;
        }
    }
    __syncthreads();     // all lx reads done; safe to reuse smem as red
    #pragma unroll
    for (int tt=0;tt<12;tt++) red[(ug*64+c)*13 + tt] = vacc[tt];
    __syncthreads();
    float vs=0.f, vq=0.f;
    for (int i = tid; i < 768; i += 256){
        int tt = i>>6, c2 = i&63;
        float tot = red[(0*64+c2)*13+tt]+red[(1*64+c2)*13+tt]
                  + red[(2*64+c2)*13+tt]+red[(3*64+c2)*13+tt];
        view_pre[n*19200 + c2*300 + t0+tt] = tot;
        vs += tot; vq += tot*tot;
    }
    #pragma unroll
    for (int o=32;o>0;o>>=1){ vs += __shfl_down(vs,o); vq += __shfl_down(vq,o); }
    if ((tid&63)==0){ rs[(tid>>6)*2]=vs; rs[(tid>>6)*2+1]=vq; }
    __syncthreads();
    if (tid==0){
        view_part[(n*25+tc)*2]   = rs[0]+rs[2]+rs[4]+rs[6];
        view_part[(n*25+tc)*2+1] = rs[1]+rs[3]+rs[5]+rs[7];
    }
}

// K2a: reduce T0 partials over 25 chunks -> T0 (u-space); block stat partials.
__global__ __launch_bounds__(256) void k2a_timereduce(
    const float* __restrict__ t0_part, float* __restrict__ time_pre,
    float* __restrict__ tstat_part)
{
    int g = blockIdx.x*256 + threadIdx.x;   // [0, 102400)
    int n = g / 1600, r = g % 1600;
    float s = 0.f;
    for (int tc=0; tc<25; tc++) s += t0_part[(n*25+tc)*1600 + r];
    time_pre[g] = s;
    float a = s, b = s*s;
    __shared__ float ls[8];
    #pragma unroll
    for (int o=32;o>0;o>>=1){ a += __shfl_down(a,o); b += __shfl_down(b,o); }
    int wid = threadIdx.x >> 6;
    if ((threadIdx.x & 63) == 0){ ls[wid*2] = a; ls[wid*2+1] = b; }
    __syncthreads();
    if (threadIdx.x == 0){
        tstat_part[blockIdx.x*2]   = ls[0]+ls[2]+ls[4]+ls[6];
        tstat_part[blockIdx.x*2+1] = ls[1]+ls[3]+ls[5]+ls[7];
    }
}

// K2b: final scalar BN stats for view/time branches.
__global__ __launch_bounds__(256) void k2b_finstats(
    const float* __restrict__ view_part, const float* __restrict__ tstat_part,
    float* __restrict__ fin)
{
    float acc[4] = {0.f,0.f,0.f,0.f};
    for (int i=threadIdx.x; i<1600; i+=256){ acc[0] += view_part[2*i]; acc[1] += view_part[2*i+1]; }
    for (int i=threadIdx.x; i<400;  i+=256){ acc[2] += tstat_part[2*i]; acc[3] += tstat_part[2*i+1]; }
    __shared__ float ls[4][4];
    int wid = threadIdx.x>>6, lane = threadIdx.x&63;
    #pragma unroll
    for (int j=0;j<4;j++){
        float a = acc[j];
        #pragma unroll
        for (int o=32;o>0;o>>=1) a += __shfl_down(a,o);
        if (lane==0) ls[j][wid] = a;
    }
    __syncthreads();
    if (threadIdx.x==0){
        float VS=ls[0][0]+ls[0][1]+ls[0][2]+ls[0][3];
        float VQ=ls[1][0]+ls[1][1]+ls[1][2]+ls[1][3];
        float TS=ls[2][0]+ls[2][1]+ls[2][2]+ls[2][3];
        float TQ=ls[3][0]+ls[3][1]+ls[3][2]+ls[3][3];
        float vm = VS / 1228800.f;
        float vvar = fmaxf(VQ/1228800.f - vm*vm, 0.f);
        float tm = TS / 102400.f;
        float tvar = fmaxf(TQ/102400.f - tm*tm, 0.f);
        fin[0] = vm; fin[1] = rsqrtf(vvar + EPS);
        fin[2] = tm; fin[3] = rsqrtf(tvar + EPS);
    }
}

// K3: sum2_raw[n,d,l] = sum_ch Ws[d,ch]*F(n, ch*325+l); per-d stat partials.
// Time branch now reads T0 in u-space with the rotation applied at index time.
__global__ __launch_bounds__(256) void k3_conv(
    const float* __restrict__ time_pre, const float* __restrict__ view_pre,
    const float* __restrict__ fin, const float* __restrict__ Ws,
    const float* __restrict__ g_t, const float* __restrict__ be_t,
    const float* __restrict__ g_v, const float* __restrict__ be_v,
    float* __restrict__ sum2_raw, float* __restrict__ chan_part)
{
    const int n = blockIdx.y, lc = blockIdx.x;
    const int tid = threadIdx.x, lane = tid & 63, w = tid >> 6;
    const int l = lc*64 + lane;
    __shared__ float Ft[64][64];    // [ch][l-lane]
    __shared__ float Wst[64][64];   // [ch][d]
    for (int i = tid; i < 4096; i += 256){
        int d = i>>6, ch = i&63;
        Wst[ch][d] = Ws[i];
    }
    const float vm = fin[0], vi = fin[1], tm = fin[2], ti = fin[3];
    const float gt = g_t[0]*ti, bt = be_t[0] - tm*g_t[0]*ti;
    const float gv = g_v[0]*vi, bv = be_v[0] - vm*g_v[0]*vi;
    const bool lval = (l < 325);
    for (int k=0;k<16;k++){
        int ch = w + 4*k;
        float val = 0.f;
        if (lval){
            int idx = ch*325 + l;
            if (idx < 1600){
                int cc = idx/25, vv = idx - cc*25;
                int cmm = cc - ((cc>=50)?50:((cc>=25)?25:0));
                int uu = vv + cmm; if (uu >= 25) uu -= 25;
                val = hsw(time_pre[n*1600 + cc*25 + uu]*gt + bt);
            }
            else val = hsw(view_pre[n*19200 + idx - 1600]*gv + bv);
        }
        Ft[ch][lane] = val;
    }
    __syncthreads();
    float acc[16];
    #pragma unroll
    for (int k=0;k<16;k++) acc[k]=0.f;
    const int d0 = w*16;
    #pragma unroll 4
    for (int ch=0; ch<64; ch++){
        float f = Ft[ch][lane];
        #pragma unroll
        for (int dd=0; dd<16; dd++)
            acc[dd] = fmaf(f, Wst[ch][d0+dd], acc[dd]);
    }
    #pragma unroll 1
    for (int dd=0; dd<16; dd++){
        int d = d0 + dd;
        float a = lval ? acc[dd] : 0.f;
        if (lval) sum2_raw[n*20800 + d*325 + l] = a;
        float s = a, q = a*a;
        #pragma unroll
        for (int o=32;o>0;o>>=1){ s += __shfl_down(s,o); q += __shfl_down(q,o); }
        if (lane == 0){
            int b = n*6 + lc;
            chan_part[b*128 + d*2]   = s;
            chan_part[b*128 + d*2+1] = q;
        }
    }
}

// K4: per-channel BN stats.
__global__ void k4_chanstats(const float* __restrict__ chan_part, float* __restrict__ chan_stats)
{
    int d = threadIdx.x;
    float S=0.f, Q=0.f;
    for (int b=0;b<384;b++){ S += chan_part[b*128 + d*2]; Q += chan_part[b*128 + d*2+1]; }
    float m = S/20800.f;
    float var = fmaxf(Q/20800.f - m*m, 0.f);
    chan_stats[d*2] = m;
    chan_stats[d*2+1] = rsqrtf(var + EPS);
}

// K5: xbar[d,l] = mean_n hswish(bn(sum2_raw)).
__global__ __launch_bounds__(256) void k5_xbar(
    const float* __restrict__ sum2_raw, const float* __restrict__ chan_stats,
    const float* __restrict__ g_s, const float* __restrict__ be_s,
    float* __restrict__ xbar)
{
    int g = blockIdx.x*256 + threadIdx.x;
    if (g >= 20800) return;
    int d = g / 325;
    float m = chan_stats[d*2], istd = chan_stats[d*2+1];
    float ga = g_s[d]*istd, bb = be_s[d] - m*ga;
    float acc = 0.f;
    for (int n=0;n<64;n++) acc += hsw(sum2_raw[n*20800 + g]*ga + bb);
    xbar[g] = acc * (1.f/64.f);
}

// K6: gates. l<300 -> x_time output (sigmoid); l>=300 -> scale[v][c]=tanh(sigmoid)+1.
__global__ __launch_bounds__(64) void k6_gates(
    const float* __restrict__ xbar, const float* __restrict__ W2t,
    const float* __restrict__ b2t, const float* __restrict__ W2v,
    const float* __restrict__ b2v, float* __restrict__ out_time,
    float* __restrict__ scale_vc)
{
    int l = blockIdx.x, tid = threadIdx.x;
    __shared__ float xb[64];
    xb[tid] = xbar[tid*325 + l];
    __syncthreads();
    if (l < 300){
        float acc = b2t[tid];
        for (int d=0; d<64; d++) acc += W2t[tid*64+d]*xb[d];
        out_time[tid*300 + l] = sigm(acc);
    } else {
        int v = l - 300;
        float acc = b2v[tid];
        for (int d=0; d<64; d++) acc += W2v[tid*64+d]*xb[d];
        scale_vc[v*64 + tid] = tanhf(sigm(acc)) + 1.f;
    }
}

// K7': fused gather+GEMM. Block (tc,n): stage x0 tile bf16 PRE-SCALED
// (scale[(u-c)%25][c] — bijection, each element used once), then
// y[row=(tt,v)][d] = sum_c lx[c][tt*25+(v+c)%25] * LwT[d][c] via MFMA.
__global__ __launch_bounds__(256) void k7_mfma(
    const float* __restrict__ x0, const float* __restrict__ scale_vc,
    const float* __restrict__ Lw, __hip_bfloat16* __restrict__ y)
{
    const int tc = blockIdx.x, n = blockIdx.y, t0 = tc*12;
    const int tid = threadIdx.x;
    __shared__ __hip_bfloat16 lx[64*302 + 16];   // [c][tt*25+u]
    __shared__ __hip_bfloat16 Bs[64*64];
    __shared__ float sc[25*65];                  // padded: stride 65 avoids 16-way conflict
    for (int i = tid; i < 1600; i += 256){
        int v = i>>6, cl = i&63;
        sc[v*65 + cl] = scale_vc[i];
    }
    for (int i = tid; i < 4096; i += 256){
        int d = i>>6, cc = i&63;
        int sw = (((cc>>3) ^ (d&7))<<3) + (cc&7);
        Bs[d*64 + sw] = __float2bfloat16(Lw[cc*64 + d]);
    }
    __syncthreads();
    const float* xb = x0 + n*480000 + t0*25;
    for (int i = tid; i < 4800; i += 256){
        int row = i/75, c4 = i - row*75;
        float4 f = *reinterpret_cast<const float4*>(xb + row*7500 + c4*4);
        float vals[4] = {f.x, f.y, f.z, f.w};
        const int rm = row - ((row>=50)?50:((row>=25)?25:0));
        int col0 = c4*4;
        union { uint2 u; __hip_bfloat16 h[4]; } pk;
        #pragma unroll
        for (int j=0;j<4;j++){
            int col = col0 + j;
            int tt = col/25;
            int u  = col - tt*25;
            int v  = u - rm; if (v < 0) v += 25;
            pk.h[j] = __float2bfloat16(vals[j] * sc[v*65 + row]);
        }
        int base = row*302 + col0;
        *reinterpret_cast<unsigned*>(&lx[base])   = pk.u.x;
        *reinterpret_cast<unsigned*>(&lx[base+2]) = pk.u.y;
    }
    __syncthreads();
    const int wave = tid>>6, lane = tid&63;
    const int lrow = lane&15, lk = lane>>4;
    bf16x8 bfr[4][2];
    #pragma unroll
    for (int nt=0;nt<4;nt++)
      #pragma unroll
      for (int ks=0;ks<2;ks++){
          int kc = ks*4 + lk, d = nt*16 + lrow;
          bfr[nt][ks] = *reinterpret_cast<const bf16x8*>(&Bs[d*64 + ((kc ^ (d&7))<<3)]);
      }
    __hip_bfloat16* yb = y + (size_t)((n*300 + t0)*25)*64;
    for (int q=0; q<5; q++){
        int mt = wave + 4*q;
        if (mt >= 19) break;
        int r0 = mt*16 + lrow;
        int r = (r0 < 300) ? r0 : 299;
        int tt = r/25, v = r - tt*25;
        bf16x8 afr[2];
        #pragma unroll
        for (int ks=0;ks<2;ks++){
            int c0 = (ks*4 + lk)*8;
            int uu = v + c0;
            uu -= (uu>=50)?50:0; uu -= (uu>=25)?25:0;
            int addr = c0*302 + tt*25 + uu;
            union { unsigned short u[8]; bf16x8 vv; } af;
            #pragma unroll
            for (int i=0;i<8;i++){
                af.u[i] = *reinterpret_cast<const unsigned short*>(&lx[addr]);
                uu++; addr += 303;
                if (uu == 25){ uu = 0; addr -= 25; }
            }
            afr[ks] = af.vv;
        }
        f32x4 acc[4];
        #pragma unroll
        for (int nt=0;nt<4;nt++) acc[nt] = (f32x4){0.f,0.f,0.f,0.f};
        #pragma unroll
        for (int nt=0;nt<4;nt++)
          #pragma unroll
          for (int ks=0;ks<2;ks++)
            acc[nt] = __builtin_amdgcn_mfma_f32_16x16x32_bf16(afr[ks], bfr[nt][ks], acc[nt], 0, 0, 0);
        int rwb = mt*16 + lk*4;
        #pragma unroll
        for (int nt=0;nt<4;nt++){
            int col = nt*16 + lrow;
            #pragma unroll
            for (int j=0;j<4;j++){
                int rw = rwb + j;
                if (rw < 300) yb[rw*64 + col] = __float2bfloat16(acc[nt][j]);
            }
        }
    }
}

// K8 v2: 1200 blocks x 16 rows; each thread owns 4-col chunks (uint2 loads).
__global__ __launch_bounds__(256) void k8_colpart(
    const __hip_bfloat16* __restrict__ y, float* __restrict__ col_part)
{
    const int b = blockIdx.x, tid = threadIdx.x;
    const int r0 = b*16;
    const bool has2 = tid < 144;
    float s0[4]={0.f,0.f,0.f,0.f}, q0[4]={0.f,0.f,0.f,0.f};
    float s1[4]={0.f,0.f,0.f,0.f}, q1[4]={0.f,0.f,0.f,0.f};
    for (int r=r0; r<r0+16; r++){
        const __hip_bfloat16* yr = y + r*1600;
        uint2 u = *reinterpret_cast<const uint2*>(yr + tid*4);
        float a0 = __uint_as_float(u.x << 16);
        float a1 = __uint_as_float(u.x & 0xffff0000u);
        float a2 = __uint_as_float(u.y << 16);
        float a3 = __uint_as_float(u.y & 0xffff0000u);
        s0[0]+=a0; q0[0]+=a0*a0; s0[1]+=a1; q0[1]+=a1*a1;
        s0[2]+=a2; q0[2]+=a2*a2; s0[3]+=a3; q0[3]+=a3*a3;
        if (has2){
            uint2 w = *reinterpret_cast<const uint2*>(yr + (tid+256)*4);
            float b0 = __uint_as_float(w.x << 16);
            float b1 = __uint_as_float(w.x & 0xffff0000u);
            float b2 = __uint_as_float(w.y << 16);
            float b3 = __uint_as_float(w.y & 0xffff0000u);
            s1[0]+=b0; q1[0]+=b0*b0; s1[1]+=b1; q1[1]+=b1*b1;
            s1[2]+=b2; q1[2]+=b2*b2; s1[3]+=b3; q1[3]+=b3*b3;
        }
    }
    float* cp = col_part + (tid*1200 + b)*8;
    #pragma unroll
    for (int e=0;e<4;e++){ cp[e] = s0[e]; cp[4+e] = q0[e]; }
    if (has2){
        float* cp2 = col_part + ((tid+256)*1200 + b)*8;
        #pragma unroll
        for (int e=0;e<4;e++){ cp2[e] = s1[e]; cp2[4+e] = q1[e]; }
    }
}

// K8b v2: one block per 4-col chunk; reduce 1200 block-partials.
__global__ __launch_bounds__(256) void k8b_colstats(
    const float* __restrict__ col_part, float* __restrict__ col_stats)
{
    const int j = blockIdx.x, tid = threadIdx.x;
    float acc[8] = {0.f,0.f,0.f,0.f,0.f,0.f,0.f,0.f};
    for (int b = tid; b < 1200; b += 256){
        const float* cp = col_part + (j*1200 + b)*8;
        float4 x0 = *reinterpret_cast<const float4*>(cp);
        float4 x1 = *reinterpret_cast<const float4*>(cp+4);
        acc[0]+=x0.x; acc[1]+=x0.y; acc[2]+=x0.z; acc[3]+=x0.w;
        acc[4]+=x1.x; acc[5]+=x1.y; acc[6]+=x1.z; acc[7]+=x1.w;
    }
    #pragma unroll
    for (int e=0;e<8;e++){
        #pragma unroll
        for (int o=32;o>0;o>>=1) acc[e] += __shfl_down(acc[e], o);
    }
    __shared__ float red[4][8];
    if ((tid&63)==0){
        #pragma unroll
        for (int e=0;e<8;e++) red[tid>>6][e] = acc[e];
    }
    __syncthreads();
    if (tid < 4){
        float S = red[0][tid]+red[1][tid]+red[2][tid]+red[3][tid];
        float Q = red[0][4+tid]+red[1][4+tid]+red[2][4+tid]+red[3][4+tid];
        float m = S/19200.f;
        float var = fmaxf(Q/19200.f - m*m, 0.f);
        int col = j*4 + tid;
        col_stats[col*2]   = m;
        col_stats[col*2+1] = rsqrtf(var + EPS);
    }
}

// K8c: colAB[s] = (A, B) for s = shift_out[j] — inverse-permuted for coalesced k9 staging.
__global__ __launch_bounds__(256) void k8c_jparams(
    const int* __restrict__ shift_out, const float* __restrict__ col_stats,
    const float* __restrict__ g_bn, const float* __restrict__ be_bn,
    float2* __restrict__ colAB)
{
    int j = blockIdx.x*256 + threadIdx.x;
    if (j >= 1600) return;
    int s = shift_out[j];
    float m = col_stats[s*2], istd = col_stats[s*2+1];
    float A = istd * g_bn[j];
    float B = be_bn[j] - m*A;
    colAB[s] = make_float2(A, B);
}

// K9 v3: permute-at-staging (unchanged from R5).
__global__ __launch_bounds__(256) void k9_final(
    const float* __restrict__ x0, const __hip_bfloat16* __restrict__ y,
    const float2* __restrict__ colAB, float* __restrict__ out)
{
    const int tc = blockIdx.x, n = blockIdx.y, t0 = tc*4;
    const int tid = threadIdx.x;
    __shared__ float ysp[64*104];     // [d][rem], rem = tt*25+v, pad 100->104
    const __hip_bfloat16* yb = y + (n*300 + t0)*1600;
    for (int i = tid; i < 1600; i += 256){
        int tt = i / 400;
        int q  = i - tt*400;
        int col0 = q*4;
        uint2 u = *reinterpret_cast<const uint2*>(yb + tt*1600 + col0);
        float4 ab01 = *reinterpret_cast<const float4*>(&colAB[col0]);
        float4 ab23 = *reinterpret_cast<const float4*>(&colAB[col0+2]);
        float yv0 = __uint_as_float(u.x << 16);
        float yv1 = __uint_as_float(u.x & 0xffff0000u);
        float yv2 = __uint_as_float(u.y << 16);
        float yv3 = __uint_as_float(u.y & 0xffff0000u);
        int m = col0 >> 6, d0 = col0 & 63;
        int vv = (m + d0) % 25;
        float vals[4] = { fmaf(yv0, ab01.x, ab01.y), fmaf(yv1, ab01.z, ab01.w),
                          fmaf(yv2, ab23.x, ab23.y), fmaf(yv3, ab23.z, ab23.w) };
        int base = tt*25;
        #pragma unroll
        for (int j=0;j<4;j++){
            int v = vv + j; if (v >= 25) v -= 25;
            ysp[(d0+j)*104 + base + v] = vals[j];
        }
    }
    __syncthreads();
    const int base_x = n*480000 + tc*100;
    for (int i = tid; i < 1600; i += 256){
        int d = i/25, ch = i - d*25;
        int rem0 = ch*4;
        int gidx = base_x + d*7500 + rem0;
        float4 xv = *reinterpret_cast<const float4*>(x0 + gidx);
        float4 yv = *reinterpret_cast<const float4*>(&ysp[d*104 + rem0]);
        float4 ov;
        ov.x = fmaxf(yv.x + xv.x, 0.f);
        ov.y = fmaxf(yv.y + xv.y, 0.f);
        ov.z = fmaxf(yv.z + xv.z, 0.f);
        ov.w = fmaxf(yv.w + xv.w, 0.f);
        *reinterpret_cast<float4*>(out + gidx) = ov;
    }
}

extern "C" void kernel_launch(void* const* d_in, const int* in_sizes, int n_in,
                              void* d_out, int out_size, void* d_ws, size_t ws_size,
                              hipStream_t stream)
{
    const float* x0       = (const float*)d_in[0];
    const int*   shift_out= (const int*)d_in[2];
    const float* Wv       = (const float*)d_in[3];
    const float* g_v      = (const float*)d_in[5];
    const float* be_v     = (const float*)d_in[6];
    const float* Wt       = (const float*)d_in[7];
    const float* g_t      = (const float*)d_in[9];
    const float* be_t     = (const float*)d_in[10];
    const float* Ws       = (const float*)d_in[11];
    const float* g_s      = (const float*)d_in[13];
    const float* be_s     = (const float*)d_in[14];
    const float* W2t      = (const float*)d_in[15];
    const float* b2t      = (const float*)d_in[16];
    const float* W2v      = (const float*)d_in[17];
    const float* b2v      = (const float*)d_in[18];
    const float* Lw       = (const float*)d_in[19];
    const float* g_bn     = (const float*)d_in[21];
    const float* be_bn    = (const float*)d_in[22];

    float* ws = (float*)d_ws;
    float* view_pre  = ws;                  // 1,228,800  (dead after k3)
    float* t0_part   = ws + 1228800;        // 2,560,000  (dead after k2a)
    float* time_pre  = ws + 3788800;        //   102,400  (dead after k3)
    float* view_part = ws + 3891200;        //     3,200  (dead after k2b)
    float* tstat_part= ws + 3894400;        //       800
    float* fin       = ws + 3895200;        //         8
    float* sum2_raw  = ws + 3895208;        // 1,331,200
    float* chan_part = ws + 5226408;        //    49,152
    float* chan_stats= ws + 5275560;        //       128
    float* xbar      = ws + 5275688;        //    20,800
    float* scale_vc  = ws + 5296488;        //     1,600
    float* col_part  = ws;                  // 3,840,000 floats — ALIASES view_pre..time_pre (dead by k8)
    float* col_stats = ws + 5810088;        //     3,200
    float2* colAB    = (float2*)(ws + 5813288); // 1,600 float2
    __hip_bfloat16* y = (__hip_bfloat16*)(ws + 5819688); // 30,720,000 bf16

    float* out      = (float*)d_out;
    float* out_time = out + 30720000;

    k1_viewtime   <<<dim3(25,64), 256, 0, stream>>>(x0, Wv, Wt, view_pre, t0_part, view_part);
    k2a_timereduce<<<400, 256, 0, stream>>>(t0_part, time_pre, tstat_part);
    k2b_finstats  <<<1, 256, 0, stream>>>(view_part, tstat_part, fin);
    k3_conv       <<<dim3(6,64), 256, 0, stream>>>(time_pre, view_pre, fin, Ws, g_t, be_t, g_v, be_v, sum2_raw, chan_part);
    k4_chanstats  <<<1, 64, 0, stream>>>(chan_part, chan_stats);
    k5_xbar       <<<82, 256, 0, stream>>>(sum2_raw, chan_stats, g_s, be_s, xbar);
    k6_gates      <<<325, 64, 0, stream>>>(xbar, W2t, b2t, W2v, b2v, out_time, scale_vc);
    k7_mfma       <<<dim3(25,64), 256, 0, stream>>>(x0, scale_vc, Lw, y);
    k8_colpart    <<<1200, 256, 0, stream>>>(y, col_part);
    k8b_colstats  <<<400, 256, 0, stream>>>(col_part, col_stats);
    k8c_jparams   <<<7, 256, 0, stream>>>(shift_out, col_stats, g_bn, be_bn, colAB);
    k9_final      <<<dim3(75,64), 256, 0, stream>>>(x0, y, colAB, out);
}

// Round 8
// 225.784 us; speedup vs baseline: 1.0407x; 1.0407x over previous
//
#include <hip/hip_runtime.h>
#include <hip/hip_bf16.h>

#define EPS 1e-5f

typedef __bf16 bf16x8 __attribute__((ext_vector_type(8)));
typedef __bf16 bf16x4 __attribute__((ext_vector_type(4)));
typedef float f32x4 __attribute__((ext_vector_type(4)));

__device__ __forceinline__ float hsw(float x){
    float t = fminf(fmaxf(x + 3.f, 0.f), 6.f);
    return x * t * (1.f/6.f);
}
__device__ __forceinline__ float sigm(float x){ return 1.f/(1.f + expf(-x)); }

// shift_in is analytically s = 64*((v+c)%25) + c  -> x[n,c,t,v] = x0[n,c,t,(v+c)%25].
// K1: pure reduce. Stage x0 tile in LDS; T0 partials (u-space) + view_pre via
// rotated weights Wv[(u-c)%25].
__global__ __launch_bounds__(256) void k1_viewtime(
    const float* __restrict__ x0, const float* __restrict__ Wv,
    const float* __restrict__ Wt, float* __restrict__ view_pre,
    float* __restrict__ t0_part, float* __restrict__ view_part)
{
    const int tc = blockIdx.x, n = blockIdx.y, t0 = tc*12;
    const int tid = threadIdx.x;
    __shared__ alignas(16) unsigned char smem[64*302*2];   // 38656 B
    __shared__ float rs[8];
    __shared__ float WvL[32];
    __hip_bfloat16* lx = (__hip_bfloat16*)smem;             // [c][tt*25+u], stride 302
    float* red = (float*)smem;                              // [w*64+c][13] after lx dead
    if (tid < 25) WvL[tid] = Wv[tid];
    const float* xb = x0 + n*480000 + t0*25;
    for (int i = tid; i < 4800; i += 256){
        int row = i/75, c4 = i - row*75;
        float4 f = *reinterpret_cast<const float4*>(xb + row*7500 + c4*4);
        union { uint2 u; __hip_bfloat16 h[4]; } pk;
        pk.h[0]=__float2bfloat16(f.x); pk.h[1]=__float2bfloat16(f.y);
        pk.h[2]=__float2bfloat16(f.z); pk.h[3]=__float2bfloat16(f.w);
        int base = row*302 + c4*4;
        *reinterpret_cast<unsigned*>(&lx[base])   = pk.u.x;
        *reinterpret_cast<unsigned*>(&lx[base+2]) = pk.u.y;
    }
    float wt[12];
    #pragma unroll
    for (int tt=0;tt<12;tt++) wt[tt] = Wt[t0+tt];
    __syncthreads();
    const int c = tid & 63, ug = tid >> 6;
    const int cm = c - ((c>=50)?50:((c>=25)?25:0));
    float vacc[12];
    #pragma unroll
    for (int tt=0;tt<12;tt++) vacc[tt]=0.f;
    for (int k=0;k<7;k++){
        int u = ug + 4*k;
        if (u < 25){
            int mm = u - cm; if (mm < 0) mm += 25;
            float wv = WvL[mm];
            int base = c*302 + u;
            float tacc = 0.f;
            #pragma unroll
            for (int tt=0;tt<12;tt++){
                float val = __bfloat162float(lx[base + tt*25]);
                tacc += wt[tt]*val;
                vacc[tt] += wv*val;
            }
            t0_part[(n*25+tc)*1600 + c*25 + u] = tacc;
        }
    }
    __syncthreads();     // all lx reads done; safe to reuse smem as red
    #pragma unroll
    for (int tt=0;tt<12;tt++) red[(ug*64+c)*13 + tt] = vacc[tt];
    __syncthreads();
    float vs=0.f, vq=0.f;
    for (int i = tid; i < 768; i += 256){
        int tt = i>>6, c2 = i&63;
        float tot = red[(0*64+c2)*13+tt]+red[(1*64+c2)*13+tt]
                  + red[(2*64+c2)*13+tt]+red[(3*64+c2)*13+tt];
        view_pre[n*19200 + c2*300 + t0+tt] = tot;
        vs += tot; vq += tot*tot;
    }
    #pragma unroll
    for (int o=32;o>0;o>>=1){ vs += __shfl_down(vs,o); vq += __shfl_down(vq,o); }
    if ((tid&63)==0){ rs[(tid>>6)*2]=vs; rs[(tid>>6)*2+1]=vq; }
    __syncthreads();
    if (tid==0){
        view_part[(n*25+tc)*2]   = rs[0]+rs[2]+rs[4]+rs[6];
        view_part[(n*25+tc)*2+1] = rs[1]+rs[3]+rs[5]+rs[7];
    }
}

// K2a: reduce T0 partials over 25 chunks -> T0 (u-space); block stat partials.
__global__ __launch_bounds__(256) void k2a_timereduce(
    const float* __restrict__ t0_part, float* __restrict__ time_pre,
    float* __restrict__ tstat_part)
{
    int g = blockIdx.x*256 + threadIdx.x;   // [0, 102400)
    int n = g / 1600, r = g % 1600;
    float s = 0.f;
    for (int tc=0; tc<25; tc++) s += t0_part[(n*25+tc)*1600 + r];
    time_pre[g] = s;
    float a = s, b = s*s;
    __shared__ float ls[8];
    #pragma unroll
    for (int o=32;o>0;o>>=1){ a += __shfl_down(a,o); b += __shfl_down(b,o); }
    int wid = threadIdx.x >> 6;
    if ((threadIdx.x & 63) == 0){ ls[wid*2] = a; ls[wid*2+1] = b; }
    __syncthreads();
    if (threadIdx.x == 0){
        tstat_part[blockIdx.x*2]   = ls[0]+ls[2]+ls[4]+ls[6];
        tstat_part[blockIdx.x*2+1] = ls[1]+ls[3]+ls[5]+ls[7];
    }
}

// K2b: final scalar BN stats for view/time branches.
__global__ __launch_bounds__(256) void k2b_finstats(
    const float* __restrict__ view_part, const float* __restrict__ tstat_part,
    float* __restrict__ fin)
{
    float acc[4] = {0.f,0.f,0.f,0.f};
    for (int i=threadIdx.x; i<1600; i+=256){ acc[0] += view_part[2*i]; acc[1] += view_part[2*i+1]; }
    for (int i=threadIdx.x; i<400;  i+=256){ acc[2] += tstat_part[2*i]; acc[3] += tstat_part[2*i+1]; }
    __shared__ float ls[4][4];
    int wid = threadIdx.x>>6, lane = threadIdx.x&63;
    #pragma unroll
    for (int j=0;j<4;j++){
        float a = acc[j];
        #pragma unroll
        for (int o=32;o>0;o>>=1) a += __shfl_down(a,o);
        if (lane==0) ls[j][wid] = a;
    }
    __syncthreads();
    if (threadIdx.x==0){
        float VS=ls[0][0]+ls[0][1]+ls[0][2]+ls[0][3];
        float VQ=ls[1][0]+ls[1][1]+ls[1][2]+ls[1][3];
        float TS=ls[2][0]+ls[2][1]+ls[2][2]+ls[2][3];
        float TQ=ls[3][0]+ls[3][1]+ls[3][2]+ls[3][3];
        float vm = VS / 1228800.f;
        float vvar = fmaxf(VQ/1228800.f - vm*vm, 0.f);
        float tm = TS / 102400.f;
        float tvar = fmaxf(TQ/102400.f - tm*tm, 0.f);
        fin[0] = vm; fin[1] = rsqrtf(vvar + EPS);
        fin[2] = tm; fin[3] = rsqrtf(tvar + EPS);
    }
}

// K3: sum2_raw[n,d,l] = sum_ch Ws[d,ch]*F(n, ch*325+l); per-d stat partials.
__global__ __launch_bounds__(256) void k3_conv(
    const float* __restrict__ time_pre, const float* __restrict__ view_pre,
    const float* __restrict__ fin, const float* __restrict__ Ws,
    const float* __restrict__ g_t, const float* __restrict__ be_t,
    const float* __restrict__ g_v, const float* __restrict__ be_v,
    float* __restrict__ sum2_raw, float* __restrict__ chan_part)
{
    const int n = blockIdx.y, lc = blockIdx.x;
    const int tid = threadIdx.x, lane = tid & 63, w = tid >> 6;
    const int l = lc*64 + lane;
    __shared__ float Ft[64][64];    // [ch][l-lane]
    __shared__ float Wst[64][64];   // [ch][d]
    for (int i = tid; i < 4096; i += 256){
        int d = i>>6, ch = i&63;
        Wst[ch][d] = Ws[i];
    }
    const float vm = fin[0], vi = fin[1], tm = fin[2], ti = fin[3];
    const float gt = g_t[0]*ti, bt = be_t[0] - tm*g_t[0]*ti;
    const float gv = g_v[0]*vi, bv = be_v[0] - vm*g_v[0]*vi;
    const bool lval = (l < 325);
    for (int k=0;k<16;k++){
        int ch = w + 4*k;
        float val = 0.f;
        if (lval){
            int idx = ch*325 + l;
            if (idx < 1600){
                int cc = idx/25, vv = idx - cc*25;
                int cmm = cc - ((cc>=50)?50:((cc>=25)?25:0));
                int uu = vv + cmm; if (uu >= 25) uu -= 25;
                val = hsw(time_pre[n*1600 + cc*25 + uu]*gt + bt);
            }
            else val = hsw(view_pre[n*19200 + idx - 1600]*gv + bv);
        }
        Ft[ch][lane] = val;
    }
    __syncthreads();
    float acc[16];
    #pragma unroll
    for (int k=0;k<16;k++) acc[k]=0.f;
    const int d0 = w*16;
    #pragma unroll 4
    for (int ch=0; ch<64; ch++){
        float f = Ft[ch][lane];
        #pragma unroll
        for (int dd=0; dd<16; dd++)
            acc[dd] = fmaf(f, Wst[ch][d0+dd], acc[dd]);
    }
    #pragma unroll 1
    for (int dd=0; dd<16; dd++){
        int d = d0 + dd;
        float a = lval ? acc[dd] : 0.f;
        if (lval) sum2_raw[n*20800 + d*325 + l] = a;
        float s = a, q = a*a;
        #pragma unroll
        for (int o=32;o>0;o>>=1){ s += __shfl_down(s,o); q += __shfl_down(q,o); }
        if (lane == 0){
            int b = n*6 + lc;
            chan_part[b*128 + d*2]   = s;
            chan_part[b*128 + d*2+1] = q;
        }
    }
}

// K4: per-channel BN stats.
__global__ void k4_chanstats(const float* __restrict__ chan_part, float* __restrict__ chan_stats)
{
    int d = threadIdx.x;
    float S=0.f, Q=0.f;
    for (int b=0;b<384;b++){ S += chan_part[b*128 + d*2]; Q += chan_part[b*128 + d*2+1]; }
    float m = S/20800.f;
    float var = fmaxf(Q/20800.f - m*m, 0.f);
    chan_stats[d*2] = m;
    chan_stats[d*2+1] = rsqrtf(var + EPS);
}

// K5: xbar partials over 16-n groups (grid 82 x 4).
__global__ __launch_bounds__(256) void k5_xbar(
    const float* __restrict__ sum2_raw, const float* __restrict__ chan_stats,
    const float* __restrict__ g_s, const float* __restrict__ be_s,
    float* __restrict__ xbar_part)
{
    int g = blockIdx.x*256 + threadIdx.x;
    if (g >= 20800) return;
    int d = g / 325;
    float m = chan_stats[d*2], istd = chan_stats[d*2+1];
    float ga = g_s[d]*istd, bb = be_s[d] - m*ga;
    float acc = 0.f;
    int n0 = blockIdx.y*16;
    for (int n=n0;n<n0+16;n++) acc += hsw(sum2_raw[n*20800 + g]*ga + bb);
    xbar_part[blockIdx.y*20800 + g] = acc;
}

// K6: gates (sums 4 xbar partials). l<300 -> x_time (sigmoid); else scale[v][c].
__global__ __launch_bounds__(64) void k6_gates(
    const float* __restrict__ xbar_part, const float* __restrict__ W2t,
    const float* __restrict__ b2t, const float* __restrict__ W2v,
    const float* __restrict__ b2v, float* __restrict__ out_time,
    float* __restrict__ scale_vc)
{
    int l = blockIdx.x, tid = threadIdx.x;
    __shared__ float xb[64];
    int o = tid*325 + l;
    xb[tid] = (xbar_part[o] + xbar_part[20800+o] + xbar_part[41600+o]
             + xbar_part[62400+o]) * (1.f/64.f);
    __syncthreads();
    if (l < 300){
        float acc = b2t[tid];
        for (int d=0; d<64; d++) acc += W2t[tid*64+d]*xb[d];
        out_time[tid*300 + l] = sigm(acc);
    } else {
        int v = l - 300;
        float acc = b2v[tid];
        for (int d=0; d<64; d++) acc += W2v[tid*64+d]*xb[d];
        scale_vc[v*64 + tid] = tanhf(sigm(acc)) + 1.f;
    }
}

// K7 v3: fused gather+GEMM with TRANSPOSED LDS tile.
// Stage lx3[row=(tt*25+v)][c] = bf16(x0[n,c,t0+tt,(v+c)%25] * sc[v][c]) (stride 68),
// then A-fragments are 2x ds_read_b64 per k-chunk. B^T XOR-swizzled as before.
__global__ __launch_bounds__(256) void k7_mfma(
    const float* __restrict__ x0, const float* __restrict__ scale_vc,
    const float* __restrict__ Lw, __hip_bfloat16* __restrict__ y)
{
    const int tc = blockIdx.x, n = blockIdx.y, t0 = tc*12;
    const int tid = threadIdx.x;
    __shared__ __hip_bfloat16 lx3[300*68];       // 40800 B
    __shared__ __hip_bfloat16 Bs[64*64];         //  8192 B
    __shared__ __hip_bfloat16 scb[25*65];        //  3250 B
    for (int i = tid; i < 1600; i += 256){
        int v = i>>6, cl = i&63;
        scb[v*65 + cl] = __float2bfloat16(scale_vc[i]);
    }
    for (int i = tid; i < 4096; i += 256){
        int d = i>>6, cc = i&63;
        int sw = (((cc>>3) ^ (d&7))<<3) + (cc&7);
        Bs[d*64 + sw] = __float2bfloat16(Lw[cc*64 + d]);
    }
    __syncthreads();
    const float* xb = x0 + n*480000 + t0*25;
    for (int i = tid; i < 4800; i += 256){
        int c = i/75, c4 = i - c*75;
        float4 f = *reinterpret_cast<const float4*>(xb + c*7500 + c4*4);
        float vals[4] = {f.x, f.y, f.z, f.w};
        const int cm = c - ((c>=50)?50:((c>=25)?25:0));
        int col0 = c4*4;
        #pragma unroll
        for (int j=0;j<4;j++){
            int col = col0 + j;
            int tt = col/25;
            int u  = col - tt*25;
            int v  = u - cm; if (v < 0) v += 25;
            float s = __bfloat162float(scb[v*65 + c]);
            lx3[(tt*25+v)*68 + c] = __float2bfloat16(vals[j]*s);
        }
    }
    __syncthreads();
    const int wave = tid>>6, lane = tid&63;
    const int lrow = lane&15, lk = lane>>4;
    bf16x8 bfr[4][2];
    #pragma unroll
    for (int nt=0;nt<4;nt++)
      #pragma unroll
      for (int ks=0;ks<2;ks++){
          int kc = ks*4 + lk, d = nt*16 + lrow;
          bfr[nt][ks] = *reinterpret_cast<const bf16x8*>(&Bs[d*64 + ((kc ^ (d&7))<<3)]);
      }
    __hip_bfloat16* yb = y + (size_t)((n*300 + t0)*25)*64;
    for (int q=0; q<5; q++){
        int mt = wave + 4*q;
        if (mt >= 19) break;
        int r0 = mt*16 + lrow;
        int r = (r0 < 300) ? r0 : 299;
        bf16x8 afr[2];
        #pragma unroll
        for (int ks=0;ks<2;ks++){
            int c0 = (ks*4 + lk)*8;
            union { bf16x4 h[2]; bf16x8 v8; } u;
            u.h[0] = *reinterpret_cast<const bf16x4*>(&lx3[r*68 + c0]);
            u.h[1] = *reinterpret_cast<const bf16x4*>(&lx3[r*68 + c0 + 4]);
            afr[ks] = u.v8;
        }
        f32x4 acc[4];
        #pragma unroll
        for (int nt=0;nt<4;nt++) acc[nt] = (f32x4){0.f,0.f,0.f,0.f};
        #pragma unroll
        for (int nt=0;nt<4;nt++)
          #pragma unroll
          for (int ks=0;ks<2;ks++)
            acc[nt] = __builtin_amdgcn_mfma_f32_16x16x32_bf16(afr[ks], bfr[nt][ks], acc[nt], 0, 0, 0);
        int rwb = mt*16 + lk*4;
        #pragma unroll
        for (int nt=0;nt<4;nt++){
            int col = nt*16 + lrow;
            #pragma unroll
            for (int j=0;j<4;j++){
                int rw = rwb + j;
                if (rw < 300) yb[rw*64 + col] = __float2bfloat16(acc[nt][j]);
            }
        }
    }
}

// K8: 1200 blocks x 16 rows; each thread owns 4-col chunks (uint2 loads).
__global__ __launch_bounds__(256) void k8_colpart(
    const __hip_bfloat16* __restrict__ y, float* __restrict__ col_part)
{
    const int b = blockIdx.x, tid = threadIdx.x;
    const int r0 = b*16;
    const bool has2 = tid < 144;
    float s0[4]={0.f,0.f,0.f,0.f}, q0[4]={0.f,0.f,0.f,0.f};
    float s1[4]={0.f,0.f,0.f,0.f}, q1[4]={0.f,0.f,0.f,0.f};
    for (int r=r0; r<r0+16; r++){
        const __hip_bfloat16* yr = y + r*1600;
        uint2 u = *reinterpret_cast<const uint2*>(yr + tid*4);
        float a0 = __uint_as_float(u.x << 16);
        float a1 = __uint_as_float(u.x & 0xffff0000u);
        float a2 = __uint_as_float(u.y << 16);
        float a3 = __uint_as_float(u.y & 0xffff0000u);
        s0[0]+=a0; q0[0]+=a0*a0; s0[1]+=a1; q0[1]+=a1*a1;
        s0[2]+=a2; q0[2]+=a2*a2; s0[3]+=a3; q0[3]+=a3*a3;
        if (has2){
            uint2 w = *reinterpret_cast<const uint2*>(yr + (tid+256)*4);
            float b0 = __uint_as_float(w.x << 16);
            float b1 = __uint_as_float(w.x & 0xffff0000u);
            float b2 = __uint_as_float(w.y << 16);
            float b3 = __uint_as_float(w.y & 0xffff0000u);
            s1[0]+=b0; q1[0]+=b0*b0; s1[1]+=b1; q1[1]+=b1*b1;
            s1[2]+=b2; q1[2]+=b2*b2; s1[3]+=b3; q1[3]+=b3*b3;
        }
    }
    float* cp = col_part + (tid*1200 + b)*8;
    #pragma unroll
    for (int e=0;e<4;e++){ cp[e] = s0[e]; cp[4+e] = q0[e]; }
    if (has2){
        float* cp2 = col_part + ((tid+256)*1200 + b)*8;
        #pragma unroll
        for (int e=0;e<4;e++){ cp2[e] = s1[e]; cp2[4+e] = q1[e]; }
    }
}

// K8b: one block per 4-col chunk; reduce 1200 block-partials.
__global__ __launch_bounds__(256) void k8b_colstats(
    const float* __restrict__ col_part, float* __restrict__ col_stats)
{
    const int j = blockIdx.x, tid = threadIdx.x;
    float acc[8] = {0.f,0.f,0.f,0.f,0.f,0.f,0.f,0.f};
    for (int b = tid; b < 1200; b += 256){
        const float* cp = col_part + (j*1200 + b)*8;
        float4 x0 = *reinterpret_cast<const float4*>(cp);
        float4 x1 = *reinterpret_cast<const float4*>(cp+4);
        acc[0]+=x0.x; acc[1]+=x0.y; acc[2]+=x0.z; acc[3]+=x0.w;
        acc[4]+=x1.x; acc[5]+=x1.y; acc[6]+=x1.z; acc[7]+=x1.w;
    }
    #pragma unroll
    for (int e=0;e<8;e++){
        #pragma unroll
        for (int o=32;o>0;o>>=1) acc[e] += __shfl_down(acc[e], o);
    }
    __shared__ float red[4][8];
    if ((tid&63)==0){
        #pragma unroll
        for (int e=0;e<8;e++) red[tid>>6][e] = acc[e];
    }
    __syncthreads();
    if (tid < 4){
        float S = red[0][tid]+red[1][tid]+red[2][tid]+red[3][tid];
        float Q = red[0][4+tid]+red[1][4+tid]+red[2][4+tid]+red[3][4+tid];
        float m = S/19200.f;
        float var = fmaxf(Q/19200.f - m*m, 0.f);
        int col = j*4 + tid;
        col_stats[col*2]   = m;
        col_stats[col*2+1] = rsqrtf(var + EPS);
    }
}

// K8c: colAB[s] = (A, B) for s = shift_out[j] — inverse-permuted for coalesced k9 staging.
__global__ __launch_bounds__(256) void k8c_jparams(
    const int* __restrict__ shift_out, const float* __restrict__ col_stats,
    const float* __restrict__ g_bn, const float* __restrict__ be_bn,
    float2* __restrict__ colAB)
{
    int j = blockIdx.x*256 + threadIdx.x;
    if (j >= 1600) return;
    int s = shift_out[j];
    float m = col_stats[s*2], istd = col_stats[s*2+1];
    float A = istd * g_bn[j];
    float B = be_bn[j] - m*A;
    colAB[s] = make_float2(A, B);
}

// K9 v4: permute-at-staging with per-row rotation idx=(rem+4d)%104 —
// scatter-writes spread over 8 banks, reads stay contiguous float4.
__global__ __launch_bounds__(256) void k9_final(
    const float* __restrict__ x0, const __hip_bfloat16* __restrict__ y,
    const float2* __restrict__ colAB, float* __restrict__ out)
{
    const int tc = blockIdx.x, n = blockIdx.y, t0 = tc*4;
    const int tid = threadIdx.x;
    __shared__ float ysp[64*104];     // [d][(rem+4d)%104]
    const __hip_bfloat16* yb = y + (n*300 + t0)*1600;
    for (int i = tid; i < 1600; i += 256){
        int tt = i / 400;
        int q  = i - tt*400;
        int col0 = q*4;
        uint2 u = *reinterpret_cast<const uint2*>(yb + tt*1600 + col0);
        float4 ab01 = *reinterpret_cast<const float4*>(&colAB[col0]);
        float4 ab23 = *reinterpret_cast<const float4*>(&colAB[col0+2]);
        float yv0 = __uint_as_float(u.x << 16);
        float yv1 = __uint_as_float(u.x & 0xffff0000u);
        float yv2 = __uint_as_float(u.y << 16);
        float yv3 = __uint_as_float(u.y & 0xffff0000u);
        int m = col0 >> 6, d0 = col0 & 63;
        int vv = (m + d0) % 25;
        float vals[4] = { fmaf(yv0, ab01.x, ab01.y), fmaf(yv1, ab01.z, ab01.w),
                          fmaf(yv2, ab23.x, ab23.y), fmaf(yv3, ab23.z, ab23.w) };
        int base = tt*25;
        #pragma unroll
        for (int j=0;j<4;j++){
            int v = vv + j; if (v >= 25) v -= 25;
            int d = d0 + j;
            int idx = base + v + 4*d;
            idx -= (idx >= 208) ? 208 : 0;
            idx -= (idx >= 104) ? 104 : 0;
            ysp[d*104 + idx] = vals[j];
        }
    }
    __syncthreads();
    const int base_x = n*480000 + tc*100;
    for (int i = tid; i < 1600; i += 256){
        int d = i/25, ch = i - d*25;
        int rem0 = ch*4;
        int idx0 = rem0 + 4*d;
        idx0 -= (idx0 >= 208) ? 208 : 0;
        idx0 -= (idx0 >= 104) ? 104 : 0;
        int gidx = base_x + d*7500 + rem0;
        float4 xv = *reinterpret_cast<const float4*>(x0 + gidx);
        float4 yv = *reinterpret_cast<const float4*>(&ysp[d*104 + idx0]);
        float4 ov;
        ov.x = fmaxf(yv.x + xv.x, 0.f);
        ov.y = fmaxf(yv.y + xv.y, 0.f);
        ov.z = fmaxf(yv.z + xv.z, 0.f);
        ov.w = fmaxf(yv.w + xv.w, 0.f);
        *reinterpret_cast<float4*>(out + gidx) = ov;
    }
}

extern "C" void kernel_launch(void* const* d_in, const int* in_sizes, int n_in,
                              void* d_out, int out_size, void* d_ws, size_t ws_size,
                              hipStream_t stream)
{
    const float* x0       = (const float*)d_in[0];
    const int*   shift_out= (const int*)d_in[2];
    const float* Wv       = (const float*)d_in[3];
    const float* g_v      = (const float*)d_in[5];
    const float* be_v     = (const float*)d_in[6];
    const float* Wt       = (const float*)d_in[7];
    const float* g_t      = (const float*)d_in[9];
    const float* be_t     = (const float*)d_in[10];
    const float* Ws       = (const float*)d_in[11];
    const float* g_s      = (const float*)d_in[13];
    const float* be_s     = (const float*)d_in[14];
    const float* W2t      = (const float*)d_in[15];
    const float* b2t      = (const float*)d_in[16];
    const float* W2v      = (const float*)d_in[17];
    const float* b2v      = (const float*)d_in[18];
    const float* Lw       = (const float*)d_in[19];
    const float* g_bn     = (const float*)d_in[21];
    const float* be_bn    = (const float*)d_in[22];

    float* ws = (float*)d_ws;
    float* view_pre  = ws;                  // 1,228,800  (dead after k3)
    float* t0_part   = ws + 1228800;        // 2,560,000  (dead after k2a)
    float* time_pre  = ws + 3788800;        //   102,400  (dead after k3)
    float* view_part = ws + 3891200;        //     3,200  (dead after k2b)
    float* tstat_part= ws + 3894400;        //       800
    float* fin       = ws + 3895200;        //         8
    float* sum2_raw  = ws + 3895208;        // 1,331,200
    float* chan_part = ws + 5226408;        //    49,152
    float* chan_stats= ws + 5275560;        //       128
    float* xbar_part = ws;                  //    83,200 — ALIASES view_pre (dead after k3; consumed by k6 before k8)
    float* scale_vc  = ws + 5296488;        //     1,600
    float* col_part  = ws;                  // 3,840,000 — ALIASES (dead by k8)
    float* col_stats = ws + 5810088;        //     3,200
    float2* colAB    = (float2*)(ws + 5813288); // 1,600 float2
    __hip_bfloat16* y = (__hip_bfloat16*)(ws + 5819688); // 30,720,000 bf16

    float* out      = (float*)d_out;
    float* out_time = out + 30720000;

    k1_viewtime   <<<dim3(25,64), 256, 0, stream>>>(x0, Wv, Wt, view_pre, t0_part, view_part);
    k2a_timereduce<<<400, 256, 0, stream>>>(t0_part, time_pre, tstat_part);
    k2b_finstats  <<<1, 256, 0, stream>>>(view_part, tstat_part, fin);
    k3_conv       <<<dim3(6,64), 256, 0, stream>>>(time_pre, view_pre, fin, Ws, g_t, be_t, g_v, be_v, sum2_raw, chan_part);
    k4_chanstats  <<<1, 64, 0, stream>>>(chan_part, chan_stats);
    k5_xbar       <<<dim3(82,4), 256, 0, stream>>>(sum2_raw, chan_stats, g_s, be_s, xbar_part);
    k6_gates      <<<325, 64, 0, stream>>>(xbar_part, W2t, b2t, W2v, b2v, out_time, scale_vc);
    k7_mfma       <<<dim3(25,64), 256, 0, stream>>>(x0, scale_vc, Lw, y);
    k8_colpart    <<<1200, 256, 0, stream>>>(y, col_part);
    k8b_colstats  <<<400, 256, 0, stream>>>(col_part, col_stats);
    k8c_jparams   <<<7, 256, 0, stream>>>(shift_out, col_stats, g_bn, be_bn, colAB);
    k9_final      <<<dim3(75,64), 256, 0, stream>>>(x0, y, colAB, out);
}